// Round 14
// baseline (257.908 us; speedup 1.0000x reference)
//
#include <hip/hip_runtime.h>

#define BATCH 8
#define HH 768
#define WW 1024
#define HW (HH*WW)
#define NPIX (BATCH*HW)            /* 6291456 */
#define RG 81
#define KG (2*RG+1)                /* 163 */
#define INVK2 (1.0f/((float)KG*(float)KG))
#define RM 7
#define EPSF 1e-3f
#define NBINS 2000
#define NEG_BIG_F (-1.0e30f)
#define NROWS (BATCH*HH)           /* 6144 row-blocks */

#define BH 48                      /* band height for kv2 (row-major vertical) */
#define NVB 512                    /* 8 img x 16 bands x 4 col-quarters */
#define BH1 24                     /* band height for fused kvh1 */
#define NVB1 (BATCH*(HH/BH1))      /* 256 blocks, 1 per CU */
#define CHM 32
#define NCHM (HH/CHM)              /* 24 chunks for vertical min filter */

/* ---------------- helpers ---------------- */

__device__ inline unsigned fkey(float f) {
    unsigned u = __float_as_uint(f);
    return (u & 0x80000000u) ? ~u : (u | 0x80000000u);
}
__device__ inline float funkey(unsigned k) {
    unsigned u = (k & 0x80000000u) ? (k & 0x7fffffffu) : ~k;
    return __uint_as_float(u);
}

/* band decode for kv2: XCD (blockIdx%8) owns image (blockIdx%8);
   256 threads x 1 col = 256-col quarter; 16 bands of 48 rows. */
__device__ inline void bandDecode(int idx, int& img, int& c, int& h0) {
    img = idx & 7;
    int j = idx >> 3;          /* 0..63 */
    int colq = j >> 4;         /* 0..3 */
    int band = j & 15;         /* 0..15 */
    c = colq * 256 + threadIdx.x;
    h0 = band * BH;
}

__device__ inline float waveInclScan(float x) {
    int lane = threadIdx.x & 63;
#pragma unroll
    for (int d = 1; d < 64; d <<= 1) {
        float u = __shfl_up(x, (unsigned)d, 64);
        if (lane >= d) x += u;
    }
    return x;
}

/* inclusive prefix over 1024 row elements (4 per thread, 256 thr) */
__device__ inline void scanRow(float v0, float v1, float v2, float v3,
                               float* cum, float* wsum) {
    int tid = threadIdx.x;
    float c0 = v0, c1 = c0 + v1, c2 = c1 + v2, c3 = c2 + v3;
    float inc = waveInclScan(c3);
    int lane = tid & 63, wv = tid >> 6;
    if (lane == 63) wsum[wv] = inc;
    __syncthreads();
    float basev = 0.f;
    if (wv > 0) basev += wsum[0];
    if (wv > 1) basev += wsum[1];
    if (wv > 2) basev += wsum[2];
    float ex = basev + inc - c3;
    cum[4 * tid + 0] = ex + c0;
    cum[4 * tid + 1] = ex + c1;
    cum[4 * tid + 2] = ex + c2;
    cum[4 * tid + 3] = ex + c3;
}

/* inclusive prefix over 1024 row elements (2 per thread, 512 thr) */
__device__ inline void scanRow512(float v0, float v1, float* cum, float* wsum) {
    int tid = threadIdx.x;
    float c0 = v0, c1 = c0 + v1;
    float inc = waveInclScan(c1);
    int lane = tid & 63, wv = tid >> 6;   /* wv in 0..7 */
    if (lane == 63) wsum[wv] = inc;
    __syncthreads();
    float basev = 0.f;
    if (wv > 0) basev += wsum[0];
    if (wv > 1) basev += wsum[1];
    if (wv > 2) basev += wsum[2];
    if (wv > 3) basev += wsum[3];
    if (wv > 4) basev += wsum[4];
    if (wv > 5) basev += wsum[5];
    if (wv > 6) basev += wsum[6];
    float ex = basev + inc - c1;
    cum[2 * tid]     = ex + c0;
    cum[2 * tid + 1] = ex + c1;
}

/* ---------------- kernels ---------------- */

/* dark channel + channel mean + per-block partial sums + fused horizontal
   min filter (block == one image row). Block 0 also initializes hist/scal. */
__global__ __launch_bounds__(256) void k_prep(const float* __restrict__ x,
                                              float* __restrict__ V1raw,
                                              float* __restrict__ mmean,
                                              float* __restrict__ hmin,
                                              float* __restrict__ pbsum,
                                              unsigned* __restrict__ scal,
                                              unsigned* __restrict__ hist) {
    int t = threadIdx.x;
    if (blockIdx.x == 0) {
        for (int i = t; i < NBINS; i += 256) hist[i] = 0u;
        if (t == 0) {
            scal[0] = 0xFFFFFFFFu;  /* minKey */
            scal[1] = 0u;           /* maxKey */
            scal[2] = 0u;           /* A-cand key */
            scal[3] = 0u;           /* any flag */
        }
    }
    int img = blockIdx.x / HH;
    int row = blockIdx.x % HH;
    int pix = row * WW + t * 4;
    size_t base = (size_t)img * 3 * HW + pix;
    float4 c0 = *(const float4*)(x + base);
    float4 c1 = *(const float4*)(x + base + HW);
    float4 c2 = *(const float4*)(x + base + 2 * (size_t)HW);
    float4 mnv, mev;
    {
        float a0 = c0.x * 255.0f, a1 = c1.x * 255.0f, a2 = c2.x * 255.0f;
        mnv.x = fminf(a0, fminf(a1, a2)); mev.x = (a0 + a1 + a2) * (1.0f / 3.0f);
        a0 = c0.y * 255.0f; a1 = c1.y * 255.0f; a2 = c2.y * 255.0f;
        mnv.y = fminf(a0, fminf(a1, a2)); mev.y = (a0 + a1 + a2) * (1.0f / 3.0f);
        a0 = c0.z * 255.0f; a1 = c1.z * 255.0f; a2 = c2.z * 255.0f;
        mnv.z = fminf(a0, fminf(a1, a2)); mev.z = (a0 + a1 + a2) * (1.0f / 3.0f);
        a0 = c0.w * 255.0f; a1 = c1.w * 255.0f; a2 = c2.w * 255.0f;
        mnv.w = fminf(a0, fminf(a1, a2)); mev.w = (a0 + a1 + a2) * (1.0f / 3.0f);
    }
    size_t po = (size_t)img * HW + pix;
    *(float4*)(V1raw + po) = mnv;
    *(float4*)(mmean + po) = mev;

    __shared__ float r[WW];
    r[4 * t + 0] = mnv.x; r[4 * t + 1] = mnv.y; r[4 * t + 2] = mnv.z; r[4 * t + 3] = mnv.w;

    float s = mev.x + mev.y + mev.z + mev.w;
#pragma unroll
    for (int d = 32; d >= 1; d >>= 1) s += __shfl_down(s, (unsigned)d, 64);
    __shared__ float wsum[4];
    int lane = t & 63, wv = t >> 6;
    if (lane == 0) wsum[wv] = s;
    __syncthreads();
    if (t == 0)
        pbsum[blockIdx.x] = wsum[0] + wsum[1] + wsum[2] + wsum[3];

    /* horizontal min cascade (r=7) */
    float v[18];
#pragma unroll
    for (int i = 0; i < 18; i++) {
        int w = 4 * t - RM + i;
        w = w < 0 ? 0 : (w > WW - 1 ? WW - 1 : w);
        v[i] = r[w];
    }
#pragma unroll
    for (int i = 0; i < 17; i++) v[i] = fminf(v[i], v[i + 1]);   /* w2 */
#pragma unroll
    for (int i = 0; i < 15; i++) v[i] = fminf(v[i], v[i + 2]);   /* w4 */
#pragma unroll
    for (int i = 0; i < 11; i++) v[i] = fminf(v[i], v[i + 4]);   /* w8 */
    float4 o;
    o.x = fminf(v[0], v[7]);
    o.y = fminf(v[1], v[8]);
    o.z = fminf(v[2], v[9]);
    o.w = fminf(v[3], v[10]);
    *(float4*)(hmin + po) = o;
}

/* vertical min filter (r=7), thread per (col, 32-row chunk), log-cascade */
__global__ __launch_bounds__(256) void k_minv(const float* __restrict__ in,
                                              float* __restrict__ out) {
    int g = blockIdx.x * 256 + threadIdx.x;
    int w = g & (WW - 1);
    int t = g >> 10;
    int b = t / NCHM;
    int ch = t - b * NCHM;
    int h0 = ch * CHM;
    const float* col = in + (size_t)b * HW + w;
    float* ocol = out + (size_t)b * HW + w;
    float v[CHM + 14];
#pragma unroll
    for (int i = 0; i < CHM + 14; i++) {
        int h = h0 - RM + i;
        h = h < 0 ? 0 : (h > HH - 1 ? HH - 1 : h);
        v[i] = col[(size_t)h * WW];
    }
#pragma unroll
    for (int i = 0; i < CHM + 13; i++) v[i] = fminf(v[i], v[i + 1]);   /* w2 */
#pragma unroll
    for (int i = 0; i < CHM + 11; i++) v[i] = fminf(v[i], v[i + 2]);   /* w4 */
#pragma unroll
    for (int i = 0; i < CHM + 7; i++)  v[i] = fminf(v[i], v[i + 4]);   /* w8 */
#pragma unroll
    for (int i = 0; i < CHM; i++)
        ocol[(size_t)(h0 + i) * WW] = fminf(v[i], v[i + 7]);           /* w15 */
}

/* FUSED GF pass: vertical running sums of I,p,I*p,I*I in registers, full
   box1 finish + a,b + box2 horizontal windows via LDS row scans, writes
   ha,hb directly (F4 intermediate never touches HBM).
   Block = one image x 1024 cols x 24-row band; 512 threads, 2 cols each. */
__global__ __launch_bounds__(512) void k_kvh1(const float* __restrict__ I,
                                              const float* __restrict__ p,
                                              float2* __restrict__ HAB) {
    __shared__ float cI[WW], cP[WW], cIp[WW], cII[WW], cA[WW], cB[WW];
    __shared__ float w0[8], w1[8], w2[8], w3[8], w4[8], w5[8];
    int img = blockIdx.x & 7;
    int band = blockIdx.x >> 3;      /* 0..31 */
    int h0 = band * BH1;
    int t = threadIdx.x;
    int c = 2 * t;                   /* cols c, c+1 */
    const float* bI = I + (size_t)img * HW + c;
    const float* bP = p + (size_t)img * HW + c;
    float* bO = (float*)(HAB + (size_t)img * HW);

    float4 A = {0,0,0,0}, B = {0,0,0,0};   /* {sI,sP,sIp,sII} cols c, c+1 */
    int jlo = h0 - RG; if (jlo < 0) jlo = 0;
    int jhi = h0 + RG - 1; if (jhi > HH - 1) jhi = HH - 1;
    {
        float2 Li[8], Lp[8];
        int j = jlo;
        for (; j + 7 <= jhi; j += 8) {
#pragma unroll
            for (int k = 0; k < 8; k++) {
                Li[k] = *(const float2*)(bI + (size_t)(j + k) * WW);
                Lp[k] = *(const float2*)(bP + (size_t)(j + k) * WW);
            }
#pragma unroll
            for (int k = 0; k < 8; k++) {
                A.x += Li[k].x; A.y += Lp[k].x; A.z += Li[k].x * Lp[k].x; A.w += Li[k].x * Li[k].x;
                B.x += Li[k].y; B.y += Lp[k].y; B.z += Li[k].y * Lp[k].y; B.w += Li[k].y * Li[k].y;
            }
        }
        for (; j <= jhi; j++) {
            float2 a = *(const float2*)(bI + (size_t)j * WW);
            float2 q = *(const float2*)(bP + (size_t)j * WW);
            A.x += a.x; A.y += q.x; A.z += a.x * q.x; A.w += a.x * a.x;
            B.x += a.y; B.y += q.y; B.z += a.y * q.y; B.w += a.y * a.y;
        }
    }

    /* preload row h0's add/sub rows */
    float2 ai, ap, si, sp;
    {
        int ra = h0 + RG; int ca = ra <= HH - 1 ? ra : HH - 1;
        ai = *(const float2*)(bI + (size_t)ca * WW);
        ap = *(const float2*)(bP + (size_t)ca * WW);
        if (ra > HH - 1) { ai = make_float2(0.f, 0.f); ap = make_float2(0.f, 0.f); }
        int rs = h0 - RG; int cs = rs >= 0 ? rs : 0;
        si = *(const float2*)(bI + (size_t)cs * WW);
        sp = *(const float2*)(bP + (size_t)cs * WW);
        if (rs < 0) { si = make_float2(0.f, 0.f); sp = make_float2(0.f, 0.f); }
    }
    for (int h = h0; h < h0 + BH1; h++) {
        /* prefetch next row's add/sub before the barrier-heavy scan region */
        float2 nai = make_float2(0.f, 0.f), nap = nai, nsi = nai, nsp = nai;
        if (h + 1 < h0 + BH1) {
            int ra = h + 1 + RG; int ca = ra <= HH - 1 ? ra : HH - 1;
            nai = *(const float2*)(bI + (size_t)ca * WW);
            nap = *(const float2*)(bP + (size_t)ca * WW);
            if (ra > HH - 1) { nai = make_float2(0.f, 0.f); nap = make_float2(0.f, 0.f); }
            int rs = h + 1 - RG; int cs = rs >= 0 ? rs : 0;
            nsi = *(const float2*)(bI + (size_t)cs * WW);
            nsp = *(const float2*)(bP + (size_t)cs * WW);
            if (rs < 0) { nsi = make_float2(0.f, 0.f); nsp = make_float2(0.f, 0.f); }
        }
        A.x += ai.x; A.y += ap.x; A.z += ai.x * ap.x; A.w += ai.x * ai.x;
        B.x += ai.y; B.y += ap.y; B.z += ai.y * ap.y; B.w += ai.y * ai.y;

        scanRow512(A.x, B.x, cI, w0);
        scanRow512(A.y, B.y, cP, w1);
        scanRow512(A.z, B.z, cIp, w2);
        scanRow512(A.w, B.w, cII, w3);
        __syncthreads();
        float av0, bv0, av1, bv1;
        {
            int hi = c + RG; if (hi > WW - 1) hi = WW - 1;
            int lo = c - RG - 1;
            float a = cI[hi], b = cP[hi], d = cIp[hi], e = cII[hi];
            if (lo >= 0) { a -= cI[lo]; b -= cP[lo]; d -= cIp[lo]; e -= cII[lo]; }
            float mI = a * INVK2, mP = b * INVK2, mIp = d * INVK2, mII = e * INVK2;
            av0 = (mIp - mI * mP) / ((mII - mI * mI) + EPSF);
            bv0 = mP - av0 * mI;
            int w = c + 1;
            hi = w + RG; if (hi > WW - 1) hi = WW - 1;
            lo = w - RG - 1;
            a = cI[hi]; b = cP[hi]; d = cIp[hi]; e = cII[hi];
            if (lo >= 0) { a -= cI[lo]; b -= cP[lo]; d -= cIp[lo]; e -= cII[lo]; }
            mI = a * INVK2; mP = b * INVK2; mIp = d * INVK2; mII = e * INVK2;
            av1 = (mIp - mI * mP) / ((mII - mI * mI) + EPSF);
            bv1 = mP - av1 * mI;
        }
        scanRow512(av0, av1, cA, w4);
        scanRow512(bv0, bv1, cB, w5);
        __syncthreads();
        {
            int hi = c + RG; if (hi > WW - 1) hi = WW - 1;
            int lo = c - RG - 1;
            float ha0 = cA[hi], hb0 = cB[hi];
            if (lo >= 0) { ha0 -= cA[lo]; hb0 -= cB[lo]; }
            int w = c + 1;
            hi = w + RG; if (hi > WW - 1) hi = WW - 1;
            lo = w - RG - 1;
            float ha1 = cA[hi], hb1 = cB[hi];
            if (lo >= 0) { ha1 -= cA[lo]; hb1 -= cB[lo]; }
            *(float4*)(bO + 2 * ((size_t)h * WW) + 2 * c) = make_float4(ha0, hb0, ha1, hb1);
        }
        A.x -= si.x; A.y -= sp.x; A.z -= si.x * sp.x; A.w -= si.x * si.x;
        B.x -= si.y; B.y -= sp.y; B.z -= si.y * sp.y; B.w -= si.y * si.y;
        ai = nai; ap = nap; si = nsi; sp = nsp;
    }
}

/* GF vertical pass 2, row-major bands: sliding column sums of ha,hb;
   V1 = sum_a*INVK2*I + sum_b*INVK2; block min/max -> device atomics. */
__global__ __launch_bounds__(256) void k_kv2(const float2* __restrict__ HAB,
                                             const float* __restrict__ I,
                                             float* __restrict__ V1,
                                             unsigned* __restrict__ scal) {
    int img, c, h0;
    bandDecode(blockIdx.x, img, c, h0);
    const float2* bC = HAB + (size_t)img * HW + c;
    const float* bI = I + (size_t)img * HW + c;
    float* bV = V1 + (size_t)img * HW + c;

    /* acc = {sa, sb} */
    float2 s0 = {0,0}, s1 = {0,0}, s2 = {0,0}, s3 = {0,0};
    int jlo = h0 - RG; if (jlo < 0) jlo = 0;
    int jhi = h0 + RG - 1; if (jhi > HH - 1) jhi = HH - 1;
    {
        float2 L[8];
        int j = jlo;
        for (; j + 7 <= jhi; j += 8) {
#pragma unroll
            for (int k = 0; k < 8; k++) L[k] = bC[(size_t)(j + k) * WW];
            s0.x += L[0].x; s0.y += L[0].y;
            s1.x += L[1].x; s1.y += L[1].y;
            s2.x += L[2].x; s2.y += L[2].y;
            s3.x += L[3].x; s3.y += L[3].y;
            s0.x += L[4].x; s0.y += L[4].y;
            s1.x += L[5].x; s1.y += L[5].y;
            s2.x += L[6].x; s2.y += L[6].y;
            s3.x += L[7].x; s3.y += L[7].y;
        }
        for (; j <= jhi; j++) {
            float2 v = bC[(size_t)j * WW];
            s0.x += v.x; s0.y += v.y;
        }
    }
    float2 acc;
    acc.x = (s0.x + s1.x) + (s2.x + s3.x);
    acc.y = (s0.y + s1.y) + (s2.y + s3.y);

    float lmn = 3.4e38f, lmx = -3.4e38f;
    float2 A[8], S[8];
    float Iv[8];
    for (int h = h0; h < h0 + BH; h += 8) {
#pragma unroll
        for (int k = 0; k < 8; k++) {
            int ra = h + k + RG;
            int ca = ra <= HH - 1 ? ra : HH - 1;
            float2 v = bC[(size_t)ca * WW];
            if (ra > HH - 1) v = make_float2(0.f, 0.f);
            A[k] = v;
        }
#pragma unroll
        for (int k = 0; k < 8; k++) {
            int rs = h + k - RG;
            int cs = rs >= 0 ? rs : 0;
            float2 v = bC[(size_t)cs * WW];
            if (rs < 0) v = make_float2(0.f, 0.f);
            S[k] = v;
        }
#pragma unroll
        for (int k = 0; k < 8; k++) Iv[k] = bI[(size_t)(h + k) * WW];
#pragma unroll
        for (int k = 0; k < 8; k++) {
            acc.x += A[k].x; acc.y += A[k].y;
            float v0 = acc.x * INVK2 * Iv[k] + acc.y * INVK2;
            bV[(size_t)(h + k) * WW] = v0;
            lmn = fminf(lmn, v0);
            lmx = fmaxf(lmx, v0);
            acc.x -= S[k].x; acc.y -= S[k].y;
        }
    }
#pragma unroll
    for (int d = 32; d >= 1; d >>= 1) {
        lmn = fminf(lmn, __shfl_down(lmn, (unsigned)d, 64));
        lmx = fmaxf(lmx, __shfl_down(lmx, (unsigned)d, 64));
    }
    __shared__ float smn[4], smx[4];
    int lane = threadIdx.x & 63, wv = threadIdx.x >> 6;
    if (lane == 0) { smn[wv] = lmn; smx[wv] = lmx; }
    __syncthreads();
    if (threadIdx.x == 0) {
        float a = fminf(fminf(smn[0], smn[1]), fminf(smn[2], smn[3]));
        float b = fmaxf(fmaxf(smx[0], smx[1]), fmaxf(smx[2], smx[3]));
        atomicMin(&scal[0], fkey(a));
        atomicMax(&scal[1], fkey(b));
    }
}

/* histogram (2000 bins over [mn,mx]), float4 reads */
__global__ __launch_bounds__(256) void k_hist(const float* __restrict__ V1,
                                              const unsigned* __restrict__ scal,
                                              unsigned* __restrict__ hist) {
    __shared__ unsigned lh[NBINS];
    for (int i = threadIdx.x; i < NBINS; i += 256) lh[i] = 0u;
    __syncthreads();
    float mn = funkey(scal[0]);
    float mx = funkey(scal[1]);
    float inv = 2000.0f / (mx - mn);
    const float4* V4 = (const float4*)V1;
    for (int i = blockIdx.x * 256 + threadIdx.x; i < NPIX / 4; i += gridDim.x * 256) {
        float4 v = V4[i];
        int i0 = (int)((v.x - mn) * inv); i0 = i0 < 0 ? 0 : (i0 > NBINS - 1 ? NBINS - 1 : i0);
        int i1 = (int)((v.y - mn) * inv); i1 = i1 < 0 ? 0 : (i1 > NBINS - 1 ? NBINS - 1 : i1);
        int i2 = (int)((v.z - mn) * inv); i2 = i2 < 0 ? 0 : (i2 > NBINS - 1 ? NBINS - 1 : i2);
        int i3 = (int)((v.w - mn) * inv); i3 = i3 < 0 ? 0 : (i3 > NBINS - 1 ? NBINS - 1 : i3);
        atomicAdd(&lh[i0], 1u);
        atomicAdd(&lh[i1], 1u);
        atomicAdd(&lh[i2], 1u);
        atomicAdd(&lh[i3], 1u);
    }
    __syncthreads();
    for (int i = threadIdx.x; i < NBINS; i += 256) {
        unsigned c = lh[i];
        if (c) atomicAdd(&hist[i], c);
    }
}

/* masked max of channel-mean where V1 >= thresh, plus any(mask).
   Threshold (count at 99.9% bin) computed inline per block from hist. */
__global__ __launch_bounds__(256) void k_amax(const float* __restrict__ V1,
                                              const float* __restrict__ mmean,
                                              const unsigned* __restrict__ hist,
                                              unsigned* __restrict__ scal) {
    __shared__ float wsum[4];
    __shared__ int smaxi[4];
    __shared__ float sthresh;
    int t = threadIdx.x;
    int lane = t & 63, wv = t >> 6;
    {
        unsigned h[8];
        float local = 0.f;
#pragma unroll
        for (int j = 0; j < 8; j++) {
            int idx = t * 8 + j;
            h[j] = (idx < NBINS) ? hist[idx] : 0u;
            local += (float)h[j];
        }
        float inc = waveInclScan(local);
        if (lane == 63) wsum[wv] = inc;
        __syncthreads();
        float basev = 0.f;
        if (wv > 0) basev += wsum[0];
        if (wv > 1) basev += wsum[1];
        if (wv > 2) basev += wsum[2];
        float cum = basev + inc - local;   /* exclusive prefix; exact (ints < 2^24) */
        int lmax = -1;
#pragma unroll
        for (int j = 0; j < 8; j++) {
            int idx = t * 8 + j;
            cum += (float)h[j];
            float d = cum / (float)NPIX;
            if (idx < NBINS && d <= 0.999f) lmax = idx;
        }
#pragma unroll
        for (int d = 32; d >= 1; d >>= 1) {
            int o = __shfl_down(lmax, (unsigned)d, 64);
            lmax = o > lmax ? o : lmax;
        }
        if (lane == 0) smaxi[wv] = lmax;
        __syncthreads();
        if (t == 0) {
            int m = smaxi[0];
            if (smaxi[1] > m) m = smaxi[1];
            if (smaxi[2] > m) m = smaxi[2];
            if (smaxi[3] > m) m = smaxi[3];
            int idx = m < 0 ? NBINS - 1 : m;  /* hist[-1] wraps in the reference */
            sthresh = (float)hist[idx];
        }
        __syncthreads();
    }
    float th = sthresh;

    float lmax = NEG_BIG_F;
    bool any = false;
    const float4* V4 = (const float4*)V1;
    const float4* M4 = (const float4*)mmean;
    for (int i = blockIdx.x * 256 + t; i < NPIX / 4; i += gridDim.x * 256) {
        float4 v = V4[i];
        if (v.x >= th || v.y >= th || v.z >= th || v.w >= th) {
            float4 m = M4[i];
            any = true;
            if (v.x >= th) lmax = fmaxf(lmax, m.x);
            if (v.y >= th) lmax = fmaxf(lmax, m.y);
            if (v.z >= th) lmax = fmaxf(lmax, m.z);
            if (v.w >= th) lmax = fmaxf(lmax, m.w);
        }
    }
#pragma unroll
    for (int d = 32; d >= 1; d >>= 1) lmax = fmaxf(lmax, __shfl_down(lmax, (unsigned)d, 64));
    unsigned long long ab = __ballot(any);
    __shared__ float smx[4];
    __shared__ unsigned sany[4];
    if (lane == 0) { smx[wv] = lmax; sany[wv] = ab ? 1u : 0u; }
    __syncthreads();
    if (t == 0) {
        float m = fmaxf(fmaxf(smx[0], smx[1]), fmaxf(smx[2], smx[3]));
        unsigned a = sany[0] | sany[1] | sany[2] | sany[3];
        if (a) {
            atomicOr(&scal[3], 1u);
            atomicMax(&scal[2], fkey(m));
        }
    }
}

/* select A (candidate vs fallback); fallback per-image means reduced from
   pbsum here. */
__global__ __launch_bounds__(256) void k_selA(const unsigned* __restrict__ scal,
                                              const float* __restrict__ pbsum,
                                              float* __restrict__ fscal) {
    __shared__ double simg[BATCH];
    __shared__ double ws[4];
    int t = threadIdx.x;
    int lane = t & 63, wv = t >> 6;
    for (int img = 0; img < BATCH; img++) {
        const float* p = pbsum + img * HH;
        double s = (double)p[t] + (double)p[t + 256] + (double)p[t + 512];
#pragma unroll
        for (int d = 32; d >= 1; d >>= 1) s += __shfl_down(s, (unsigned)d, 64);
        if (lane == 0) ws[wv] = s;
        __syncthreads();
        if (t == 0) simg[img] = ws[0] + ws[1] + ws[2] + ws[3];
        __syncthreads();
    }
    if (t == 0) {
        float A;
        if (scal[3]) {
            A = funkey(scal[2]);
        } else {
            double best = -1e300;
            for (int b = 0; b < BATCH; b++) {
                double m = simg[b] / (double)HW;
                if (m > best) best = m;
            }
            A = (float)best;
        }
        fscal[5] = A;
    }
}

/* final recovery, 4 pixels per thread */
__global__ __launch_bounds__(256) void k_final(const float* __restrict__ x,
                                               const float* __restrict__ V1,
                                               const float* __restrict__ fscal,
                                               float* __restrict__ out) {
    float A = fscal[5];
    float invA = 1.0f / A;
    int i = (blockIdx.x * 256 + threadIdx.x) * 4;  /* 0..NPIX-4 */
    int b = i / HW;
    int pix = i - b * HW;
    float4 v1 = *(const float4*)(V1 + i);
    float4 v1c, den;
    v1c.x = fminf(v1.x * 0.95f, 0.8f); den.x = 1.0f / (1.0f - v1c.x * invA);
    v1c.y = fminf(v1.y * 0.95f, 0.8f); den.y = 1.0f / (1.0f - v1c.y * invA);
    v1c.z = fminf(v1.z * 0.95f, 0.8f); den.z = 1.0f / (1.0f - v1c.z * invA);
    v1c.w = fminf(v1.w * 0.95f, 0.8f); den.w = 1.0f / (1.0f - v1c.w * invA);
    size_t o = (size_t)b * 3 * HW + pix;
#pragma unroll
    for (int c = 0; c < 3; c++) {
        float4 m = *(const float4*)(x + o);
        float4 y;
        y.x = fminf(fmaxf((m.x * 255.0f - v1c.x) * den.x, 0.0f), 1.0f);
        y.y = fminf(fmaxf((m.y * 255.0f - v1c.y) * den.y, 0.0f), 1.0f);
        y.z = fminf(fmaxf((m.z * 255.0f - v1c.z) * den.z, 0.0f), 1.0f);
        y.w = fminf(fmaxf((m.w * 255.0f - v1c.w) * den.w, 0.0f), 1.0f);
        *(float4*)(out + o) = y;
        o += HW;
    }
}

/* ---------------- launch ---------------- */

extern "C" void kernel_launch(void* const* d_in, const int* in_sizes, int n_in,
                              void* d_out, int out_size, void* d_ws, size_t ws_size,
                              hipStream_t stream) {
    const float* x = (const float*)d_in[0];
    float* out = (float*)d_out;

    unsigned* scal = (unsigned*)d_ws;                     /* [0]=minKey [1]=maxKey [2]=acandKey [3]=any */
    float* fscal = (float*)d_ws;                          /* [5]=A */
    unsigned* hist = (unsigned*)((char*)d_ws + 96);       /* [2000] */
    float* pbsum = (float*)((char*)d_ws + 8192);          /* [6144] block partials */
    float* planes = (float*)((char*)d_ws + 131072);
    float* P0 = planes + (size_t)0 * NPIX;  /* V1raw (I) */
    float* P1 = planes + (size_t)1 * NPIX;  /* mmean */
    float* P2 = planes + (size_t)2 * NPIX;  /* hmin */
    float* P3 = planes + (size_t)3 * NPIX;  /* p */
    float* P6 = planes + (size_t)6 * NPIX;  /* V1 */
    float2* HAB = (float2*)(planes + (size_t)4 * NPIX);   /* ha,hb interleaved, P4..P5 */

    k_prep<<<NROWS, 256, 0, stream>>>(x, P0, P1, P2, pbsum, scal, hist);
    k_minv<<<BATCH * NCHM * WW / 256, 256, 0, stream>>>(P2, P3);
    k_kvh1<<<NVB1, 512, 0, stream>>>(P0, P3, HAB);
    k_kv2<<<NVB, 256, 0, stream>>>(HAB, P0, P6, scal);
    k_hist<<<1024, 256, 0, stream>>>(P6, scal, hist);
    k_amax<<<1024, 256, 0, stream>>>(P6, P1, hist, scal);
    k_selA<<<1, 256, 0, stream>>>(scal, pbsum, fscal);
    k_final<<<NPIX / 1024, 256, 0, stream>>>(x, P6, fscal, out);
}

// Round 15
// 237.484 us; speedup vs baseline: 1.0860x; 1.0860x over previous
//
#include <hip/hip_runtime.h>

#define BATCH 8
#define HH 768
#define WW 1024
#define HW (HH*WW)
#define NPIX (BATCH*HW)            /* 6291456 */
#define RG 81
#define KG (2*RG+1)                /* 163 */
#define INVK2 (1.0f/((float)KG*(float)KG))
#define RM 7
#define EPSF 1e-3f
#define NBINS 2000
#define NEG_BIG_F (-1.0e30f)
#define NROWS (BATCH*HH)           /* 6144 row-blocks */

#define BH 48                      /* band height for row-major vertical passes */
#define NVB 512                    /* 8 img x 16 bands x 4 col-quarters */
#define CHM 32
#define NCHM (HH/CHM)              /* 24 chunks for vertical min filter */

/* ---------------- helpers ---------------- */

__device__ inline unsigned fkey(float f) {
    unsigned u = __float_as_uint(f);
    return (u & 0x80000000u) ? ~u : (u | 0x80000000u);
}
__device__ inline float funkey(unsigned k) {
    unsigned u = (k & 0x80000000u) ? (k & 0x7fffffffu) : ~k;
    return __uint_as_float(u);
}

/* band decode for vertical passes: XCD (blockIdx%8) owns image (blockIdx%8);
   256 threads x 1 col = 256-col quarter; 16 bands of 48 rows. */
__device__ inline void bandDecode(int idx, int& img, int& c, int& h0) {
    img = idx & 7;
    int j = idx >> 3;          /* 0..63 */
    int colq = j >> 4;         /* 0..3 */
    int band = j & 15;         /* 0..15 */
    c = colq * 256 + threadIdx.x;
    h0 = band * BH;
}

__device__ inline float waveInclScan(float x) {
    int lane = threadIdx.x & 63;
#pragma unroll
    for (int d = 1; d < 64; d <<= 1) {
        float u = __shfl_up(x, (unsigned)d, 64);
        if (lane >= d) x += u;
    }
    return x;
}

/* inclusive prefix over 1024 row elements (4 per thread), result into cum[0..1023] */
__device__ inline void scanRow(float v0, float v1, float v2, float v3,
                               float* cum, float* wsum) {
    int tid = threadIdx.x;
    float c0 = v0, c1 = c0 + v1, c2 = c1 + v2, c3 = c2 + v3;
    float inc = waveInclScan(c3);
    int lane = tid & 63, wv = tid >> 6;
    if (lane == 63) wsum[wv] = inc;
    __syncthreads();
    float basev = 0.f;
    if (wv > 0) basev += wsum[0];
    if (wv > 1) basev += wsum[1];
    if (wv > 2) basev += wsum[2];
    float ex = basev + inc - c3;
    cum[4 * tid + 0] = ex + c0;
    cum[4 * tid + 1] = ex + c1;
    cum[4 * tid + 2] = ex + c2;
    cum[4 * tid + 3] = ex + c3;
}

/* ---------------- kernels ---------------- */

/* dark channel + channel mean + per-block partial sums + fused horizontal
   min filter (block == one image row). Block 0 also initializes hist/scal. */
__global__ __launch_bounds__(256) void k_prep(const float* __restrict__ x,
                                              float* __restrict__ V1raw,
                                              float* __restrict__ mmean,
                                              float* __restrict__ hmin,
                                              float* __restrict__ pbsum,
                                              unsigned* __restrict__ scal,
                                              unsigned* __restrict__ hist) {
    int t = threadIdx.x;
    if (blockIdx.x == 0) {
        for (int i = t; i < NBINS; i += 256) hist[i] = 0u;
        if (t == 0) {
            scal[0] = 0xFFFFFFFFu;  /* minKey */
            scal[1] = 0u;           /* maxKey */
            scal[2] = 0u;           /* A-cand key */
            scal[3] = 0u;           /* any flag */
        }
    }
    int img = blockIdx.x / HH;
    int row = blockIdx.x % HH;
    int pix = row * WW + t * 4;
    size_t base = (size_t)img * 3 * HW + pix;
    float4 c0 = *(const float4*)(x + base);
    float4 c1 = *(const float4*)(x + base + HW);
    float4 c2 = *(const float4*)(x + base + 2 * (size_t)HW);
    float4 mnv, mev;
    {
        float a0 = c0.x * 255.0f, a1 = c1.x * 255.0f, a2 = c2.x * 255.0f;
        mnv.x = fminf(a0, fminf(a1, a2)); mev.x = (a0 + a1 + a2) * (1.0f / 3.0f);
        a0 = c0.y * 255.0f; a1 = c1.y * 255.0f; a2 = c2.y * 255.0f;
        mnv.y = fminf(a0, fminf(a1, a2)); mev.y = (a0 + a1 + a2) * (1.0f / 3.0f);
        a0 = c0.z * 255.0f; a1 = c1.z * 255.0f; a2 = c2.z * 255.0f;
        mnv.z = fminf(a0, fminf(a1, a2)); mev.z = (a0 + a1 + a2) * (1.0f / 3.0f);
        a0 = c0.w * 255.0f; a1 = c1.w * 255.0f; a2 = c2.w * 255.0f;
        mnv.w = fminf(a0, fminf(a1, a2)); mev.w = (a0 + a1 + a2) * (1.0f / 3.0f);
    }
    size_t po = (size_t)img * HW + pix;
    *(float4*)(V1raw + po) = mnv;
    *(float4*)(mmean + po) = mev;

    __shared__ float r[WW];
    r[4 * t + 0] = mnv.x; r[4 * t + 1] = mnv.y; r[4 * t + 2] = mnv.z; r[4 * t + 3] = mnv.w;

    float s = mev.x + mev.y + mev.z + mev.w;
#pragma unroll
    for (int d = 32; d >= 1; d >>= 1) s += __shfl_down(s, (unsigned)d, 64);
    __shared__ float wsum[4];
    int lane = t & 63, wv = t >> 6;
    if (lane == 0) wsum[wv] = s;
    __syncthreads();
    if (t == 0)
        pbsum[blockIdx.x] = wsum[0] + wsum[1] + wsum[2] + wsum[3];

    /* horizontal min cascade (r=7) */
    float v[18];
#pragma unroll
    for (int i = 0; i < 18; i++) {
        int w = 4 * t - RM + i;
        w = w < 0 ? 0 : (w > WW - 1 ? WW - 1 : w);
        v[i] = r[w];
    }
#pragma unroll
    for (int i = 0; i < 17; i++) v[i] = fminf(v[i], v[i + 1]);   /* w2 */
#pragma unroll
    for (int i = 0; i < 15; i++) v[i] = fminf(v[i], v[i + 2]);   /* w4 */
#pragma unroll
    for (int i = 0; i < 11; i++) v[i] = fminf(v[i], v[i + 4]);   /* w8 */
    float4 o;
    o.x = fminf(v[0], v[7]);
    o.y = fminf(v[1], v[8]);
    o.z = fminf(v[2], v[9]);
    o.w = fminf(v[3], v[10]);
    *(float4*)(hmin + po) = o;
}

/* vertical min filter (r=7), thread per (col, 32-row chunk), log-cascade */
__global__ __launch_bounds__(256) void k_minv(const float* __restrict__ in,
                                              float* __restrict__ out) {
    int g = blockIdx.x * 256 + threadIdx.x;
    int w = g & (WW - 1);
    int t = g >> 10;
    int b = t / NCHM;
    int ch = t - b * NCHM;
    int h0 = ch * CHM;
    const float* col = in + (size_t)b * HW + w;
    float* ocol = out + (size_t)b * HW + w;
    float v[CHM + 14];
#pragma unroll
    for (int i = 0; i < CHM + 14; i++) {
        int h = h0 - RM + i;
        h = h < 0 ? 0 : (h > HH - 1 ? HH - 1 : h);
        v[i] = col[(size_t)h * WW];
    }
#pragma unroll
    for (int i = 0; i < CHM + 13; i++) v[i] = fminf(v[i], v[i + 1]);   /* w2 */
#pragma unroll
    for (int i = 0; i < CHM + 11; i++) v[i] = fminf(v[i], v[i + 2]);   /* w4 */
#pragma unroll
    for (int i = 0; i < CHM + 7; i++)  v[i] = fminf(v[i], v[i + 4]);   /* w8 */
#pragma unroll
    for (int i = 0; i < CHM; i++)
        ocol[(size_t)(h0 + i) * WW] = fminf(v[i], v[i + 7]);           /* w15 */
}

/* GF vertical pass 1, row-major bands: running column sums of I, p, I*p, I*I.
   Block = 48-row band x 256 cols; thread owns 1 column; all global accesses
   are contiguous row segments. OOB add/sub rows are zero-masked. */
__global__ __launch_bounds__(256) void k_kv1(const float* __restrict__ I,
                                             const float* __restrict__ p,
                                             float4* __restrict__ F4) {
    int img, c, h0;
    bandDecode(blockIdx.x, img, c, h0);
    const float* bI = I + (size_t)img * HW + c;
    const float* bP = p + (size_t)img * HW + c;
    float4* bO = F4 + (size_t)img * HW + c;

    float4 A = {0,0,0,0};   /* {sI,sP,sIp,sII} */
    int jlo = h0 - RG; if (jlo < 0) jlo = 0;
    int jhi = h0 + RG - 1; if (jhi > HH - 1) jhi = HH - 1;
    {
        float Li[8], Lp[8];
        int j = jlo;
        for (; j + 7 <= jhi; j += 8) {
#pragma unroll
            for (int k = 0; k < 8; k++) {
                Li[k] = bI[(size_t)(j + k) * WW];
                Lp[k] = bP[(size_t)(j + k) * WW];
            }
#pragma unroll
            for (int k = 0; k < 8; k++) {
                A.x += Li[k]; A.y += Lp[k]; A.z += Li[k] * Lp[k]; A.w += Li[k] * Li[k];
            }
        }
        for (; j <= jhi; j++) {
            float a = bI[(size_t)j * WW], q = bP[(size_t)j * WW];
            A.x += a; A.y += q; A.z += a * q; A.w += a * a;
        }
    }

    float Ai[8], Ap[8], Si[8], Sp[8];
    for (int h = h0; h < h0 + BH; h += 8) {
#pragma unroll
        for (int k = 0; k < 8; k++) {
            int ra = h + k + RG;
            int ca = ra <= HH - 1 ? ra : HH - 1;
            float a = bI[(size_t)ca * WW];
            float q = bP[(size_t)ca * WW];
            if (ra > HH - 1) { a = 0.f; q = 0.f; }
            Ai[k] = a; Ap[k] = q;
        }
#pragma unroll
        for (int k = 0; k < 8; k++) {
            int rs = h + k - RG;
            int cs = rs >= 0 ? rs : 0;
            float a = bI[(size_t)cs * WW];
            float q = bP[(size_t)cs * WW];
            if (rs < 0) { a = 0.f; q = 0.f; }
            Si[k] = a; Sp[k] = q;
        }
#pragma unroll
        for (int k = 0; k < 8; k++) {
            A.x += Ai[k]; A.y += Ap[k]; A.z += Ai[k] * Ap[k]; A.w += Ai[k] * Ai[k];
            bO[(size_t)(h + k) * WW] = A;
            A.x -= Si[k]; A.y -= Sp[k]; A.z -= Si[k] * Sp[k]; A.w -= Si[k] * Si[k];
        }
    }
}

/* GF horizontal pass: complete box1 sums via row scans -> a,b; then fuse
   box2's horizontal window: row scans of a,b -> windowed sums ha,hb. */
__global__ __launch_bounds__(256) void k_kh1(const float4* __restrict__ F4,
                                             float2* __restrict__ HAB) {
    __shared__ float cI[WW], cP[WW], cIp[WW], cII[WW];
    __shared__ float cA[WW], cB[WW];
    __shared__ float w0[4], w1[4], w2[4], w3[4], w4[4], w5[4];
    size_t base = (size_t)blockIdx.x * WW;
    int t = threadIdx.x;
    float4 q0 = F4[base + 4 * t + 0];
    float4 q1 = F4[base + 4 * t + 1];
    float4 q2 = F4[base + 4 * t + 2];
    float4 q3 = F4[base + 4 * t + 3];
    scanRow(q0.x, q1.x, q2.x, q3.x, cI, w0);
    scanRow(q0.y, q1.y, q2.y, q3.y, cP, w1);
    scanRow(q0.z, q1.z, q2.z, q3.z, cIp, w2);
    scanRow(q0.w, q1.w, q2.w, q3.w, cII, w3);
    __syncthreads();
    float av[4], bv[4];
#pragma unroll
    for (int j = 0; j < 4; j++) {
        int w = 4 * t + j;
        int hi = w + RG; if (hi > WW - 1) hi = WW - 1;
        int lo = w - RG - 1;
        float a = cI[hi], b = cP[hi], c = cIp[hi], d = cII[hi];
        if (lo >= 0) { a -= cI[lo]; b -= cP[lo]; c -= cIp[lo]; d -= cII[lo]; }
        float mI = a * INVK2, mP = b * INVK2, mIp = c * INVK2, mII = d * INVK2;
        float aa = (mIp - mI * mP) / ((mII - mI * mI) + EPSF);
        av[j] = aa; bv[j] = mP - aa * mI;
    }
    __syncthreads();   /* all reads of cI..cII done before any reuse barriers below */
    scanRow(av[0], av[1], av[2], av[3], cA, w4);
    scanRow(bv[0], bv[1], bv[2], bv[3], cB, w5);
    __syncthreads();
    float oa[4], ob[4];
#pragma unroll
    for (int j = 0; j < 4; j++) {
        int w = 4 * t + j;
        int hi = w + RG; if (hi > WW - 1) hi = WW - 1;
        int lo = w - RG - 1;
        float a = cA[hi], b = cB[hi];
        if (lo >= 0) { a -= cA[lo]; b -= cB[lo]; }
        oa[j] = a; ob[j] = b;
    }
    ((float4*)(HAB + base))[2 * t]     = make_float4(oa[0], ob[0], oa[1], ob[1]);
    ((float4*)(HAB + base))[2 * t + 1] = make_float4(oa[2], ob[2], oa[3], ob[3]);
}

/* GF vertical pass 2, row-major bands: sliding column sums of ha,hb;
   V1 = sum_a*INVK2*I + sum_b*INVK2; block min/max -> device atomics. */
__global__ __launch_bounds__(256) void k_kv2(const float2* __restrict__ HAB,
                                             const float* __restrict__ I,
                                             float* __restrict__ V1,
                                             unsigned* __restrict__ scal) {
    int img, c, h0;
    bandDecode(blockIdx.x, img, c, h0);
    const float2* bC = HAB + (size_t)img * HW + c;
    const float* bI = I + (size_t)img * HW + c;
    float* bV = V1 + (size_t)img * HW + c;

    /* acc = {sa, sb} */
    float2 s0 = {0,0}, s1 = {0,0}, s2 = {0,0}, s3 = {0,0};
    int jlo = h0 - RG; if (jlo < 0) jlo = 0;
    int jhi = h0 + RG - 1; if (jhi > HH - 1) jhi = HH - 1;
    {
        float2 L[8];
        int j = jlo;
        for (; j + 7 <= jhi; j += 8) {
#pragma unroll
            for (int k = 0; k < 8; k++) L[k] = bC[(size_t)(j + k) * WW];
            s0.x += L[0].x; s0.y += L[0].y;
            s1.x += L[1].x; s1.y += L[1].y;
            s2.x += L[2].x; s2.y += L[2].y;
            s3.x += L[3].x; s3.y += L[3].y;
            s0.x += L[4].x; s0.y += L[4].y;
            s1.x += L[5].x; s1.y += L[5].y;
            s2.x += L[6].x; s2.y += L[6].y;
            s3.x += L[7].x; s3.y += L[7].y;
        }
        for (; j <= jhi; j++) {
            float2 v = bC[(size_t)j * WW];
            s0.x += v.x; s0.y += v.y;
        }
    }
    float2 acc;
    acc.x = (s0.x + s1.x) + (s2.x + s3.x);
    acc.y = (s0.y + s1.y) + (s2.y + s3.y);

    float lmn = 3.4e38f, lmx = -3.4e38f;
    float2 A[8], S[8];
    float Iv[8];
    for (int h = h0; h < h0 + BH; h += 8) {
#pragma unroll
        for (int k = 0; k < 8; k++) {
            int ra = h + k + RG;
            int ca = ra <= HH - 1 ? ra : HH - 1;
            float2 v = bC[(size_t)ca * WW];
            if (ra > HH - 1) v = make_float2(0.f, 0.f);
            A[k] = v;
        }
#pragma unroll
        for (int k = 0; k < 8; k++) {
            int rs = h + k - RG;
            int cs = rs >= 0 ? rs : 0;
            float2 v = bC[(size_t)cs * WW];
            if (rs < 0) v = make_float2(0.f, 0.f);
            S[k] = v;
        }
#pragma unroll
        for (int k = 0; k < 8; k++) Iv[k] = bI[(size_t)(h + k) * WW];
#pragma unroll
        for (int k = 0; k < 8; k++) {
            acc.x += A[k].x; acc.y += A[k].y;
            float v0 = acc.x * INVK2 * Iv[k] + acc.y * INVK2;
            bV[(size_t)(h + k) * WW] = v0;
            lmn = fminf(lmn, v0);
            lmx = fmaxf(lmx, v0);
            acc.x -= S[k].x; acc.y -= S[k].y;
        }
    }
#pragma unroll
    for (int d = 32; d >= 1; d >>= 1) {
        lmn = fminf(lmn, __shfl_down(lmn, (unsigned)d, 64));
        lmx = fmaxf(lmx, __shfl_down(lmx, (unsigned)d, 64));
    }
    __shared__ float smn[4], smx[4];
    int lane = threadIdx.x & 63, wv = threadIdx.x >> 6;
    if (lane == 0) { smn[wv] = lmn; smx[wv] = lmx; }
    __syncthreads();
    if (threadIdx.x == 0) {
        float a = fminf(fminf(smn[0], smn[1]), fminf(smn[2], smn[3]));
        float b = fmaxf(fmaxf(smx[0], smx[1]), fmaxf(smx[2], smx[3]));
        atomicMin(&scal[0], fkey(a));
        atomicMax(&scal[1], fkey(b));
    }
}

/* histogram (2000 bins over [mn,mx]), float4 reads */
__global__ __launch_bounds__(256) void k_hist(const float* __restrict__ V1,
                                              const unsigned* __restrict__ scal,
                                              unsigned* __restrict__ hist) {
    __shared__ unsigned lh[NBINS];
    for (int i = threadIdx.x; i < NBINS; i += 256) lh[i] = 0u;
    __syncthreads();
    float mn = funkey(scal[0]);
    float mx = funkey(scal[1]);
    float inv = 2000.0f / (mx - mn);
    const float4* V4 = (const float4*)V1;
    for (int i = blockIdx.x * 256 + threadIdx.x; i < NPIX / 4; i += gridDim.x * 256) {
        float4 v = V4[i];
        int i0 = (int)((v.x - mn) * inv); i0 = i0 < 0 ? 0 : (i0 > NBINS - 1 ? NBINS - 1 : i0);
        int i1 = (int)((v.y - mn) * inv); i1 = i1 < 0 ? 0 : (i1 > NBINS - 1 ? NBINS - 1 : i1);
        int i2 = (int)((v.z - mn) * inv); i2 = i2 < 0 ? 0 : (i2 > NBINS - 1 ? NBINS - 1 : i2);
        int i3 = (int)((v.w - mn) * inv); i3 = i3 < 0 ? 0 : (i3 > NBINS - 1 ? NBINS - 1 : i3);
        atomicAdd(&lh[i0], 1u);
        atomicAdd(&lh[i1], 1u);
        atomicAdd(&lh[i2], 1u);
        atomicAdd(&lh[i3], 1u);
    }
    __syncthreads();
    for (int i = threadIdx.x; i < NBINS; i += 256) {
        unsigned c = lh[i];
        if (c) atomicAdd(&hist[i], c);
    }
}

/* masked max of channel-mean where V1 >= thresh, plus any(mask).
   Threshold (count at 99.9% bin) computed inline per block from hist. */
__global__ __launch_bounds__(256) void k_amax(const float* __restrict__ V1,
                                              const float* __restrict__ mmean,
                                              const unsigned* __restrict__ hist,
                                              unsigned* __restrict__ scal) {
    __shared__ float wsum[4];
    __shared__ int smaxi[4];
    __shared__ float sthresh;
    int t = threadIdx.x;
    int lane = t & 63, wv = t >> 6;
    {
        unsigned h[8];
        float local = 0.f;
#pragma unroll
        for (int j = 0; j < 8; j++) {
            int idx = t * 8 + j;
            h[j] = (idx < NBINS) ? hist[idx] : 0u;
            local += (float)h[j];
        }
        float inc = waveInclScan(local);
        if (lane == 63) wsum[wv] = inc;
        __syncthreads();
        float basev = 0.f;
        if (wv > 0) basev += wsum[0];
        if (wv > 1) basev += wsum[1];
        if (wv > 2) basev += wsum[2];
        float cum = basev + inc - local;   /* exclusive prefix; exact (ints < 2^24) */
        int lmax = -1;
#pragma unroll
        for (int j = 0; j < 8; j++) {
            int idx = t * 8 + j;
            cum += (float)h[j];
            float d = cum / (float)NPIX;
            if (idx < NBINS && d <= 0.999f) lmax = idx;
        }
#pragma unroll
        for (int d = 32; d >= 1; d >>= 1) {
            int o = __shfl_down(lmax, (unsigned)d, 64);
            lmax = o > lmax ? o : lmax;
        }
        if (lane == 0) smaxi[wv] = lmax;
        __syncthreads();
        if (t == 0) {
            int m = smaxi[0];
            if (smaxi[1] > m) m = smaxi[1];
            if (smaxi[2] > m) m = smaxi[2];
            if (smaxi[3] > m) m = smaxi[3];
            int idx = m < 0 ? NBINS - 1 : m;  /* hist[-1] wraps in the reference */
            sthresh = (float)hist[idx];
        }
        __syncthreads();
    }
    float th = sthresh;

    float lmax = NEG_BIG_F;
    bool any = false;
    const float4* V4 = (const float4*)V1;
    const float4* M4 = (const float4*)mmean;
    for (int i = blockIdx.x * 256 + t; i < NPIX / 4; i += gridDim.x * 256) {
        float4 v = V4[i];
        if (v.x >= th || v.y >= th || v.z >= th || v.w >= th) {
            float4 m = M4[i];
            any = true;
            if (v.x >= th) lmax = fmaxf(lmax, m.x);
            if (v.y >= th) lmax = fmaxf(lmax, m.y);
            if (v.z >= th) lmax = fmaxf(lmax, m.z);
            if (v.w >= th) lmax = fmaxf(lmax, m.w);
        }
    }
#pragma unroll
    for (int d = 32; d >= 1; d >>= 1) lmax = fmaxf(lmax, __shfl_down(lmax, (unsigned)d, 64));
    unsigned long long ab = __ballot(any);
    __shared__ float smx[4];
    __shared__ unsigned sany[4];
    if (lane == 0) { smx[wv] = lmax; sany[wv] = ab ? 1u : 0u; }
    __syncthreads();
    if (t == 0) {
        float m = fmaxf(fmaxf(smx[0], smx[1]), fmaxf(smx[2], smx[3]));
        unsigned a = sany[0] | sany[1] | sany[2] | sany[3];
        if (a) {
            atomicOr(&scal[3], 1u);
            atomicMax(&scal[2], fkey(m));
        }
    }
}

/* select A (candidate vs fallback); fallback per-image means reduced from
   pbsum here. */
__global__ __launch_bounds__(256) void k_selA(const unsigned* __restrict__ scal,
                                              const float* __restrict__ pbsum,
                                              float* __restrict__ fscal) {
    __shared__ double simg[BATCH];
    __shared__ double ws[4];
    int t = threadIdx.x;
    int lane = t & 63, wv = t >> 6;
    for (int img = 0; img < BATCH; img++) {
        const float* p = pbsum + img * HH;
        double s = (double)p[t] + (double)p[t + 256] + (double)p[t + 512];
#pragma unroll
        for (int d = 32; d >= 1; d >>= 1) s += __shfl_down(s, (unsigned)d, 64);
        if (lane == 0) ws[wv] = s;
        __syncthreads();
        if (t == 0) simg[img] = ws[0] + ws[1] + ws[2] + ws[3];
        __syncthreads();
    }
    if (t == 0) {
        float A;
        if (scal[3]) {
            A = funkey(scal[2]);
        } else {
            double best = -1e300;
            for (int b = 0; b < BATCH; b++) {
                double m = simg[b] / (double)HW;
                if (m > best) best = m;
            }
            A = (float)best;
        }
        fscal[5] = A;
    }
}

/* final recovery, 4 pixels per thread */
__global__ __launch_bounds__(256) void k_final(const float* __restrict__ x,
                                               const float* __restrict__ V1,
                                               const float* __restrict__ fscal,
                                               float* __restrict__ out) {
    float A = fscal[5];
    float invA = 1.0f / A;
    int i = (blockIdx.x * 256 + threadIdx.x) * 4;  /* 0..NPIX-4 */
    int b = i / HW;
    int pix = i - b * HW;
    float4 v1 = *(const float4*)(V1 + i);
    float4 v1c, den;
    v1c.x = fminf(v1.x * 0.95f, 0.8f); den.x = 1.0f / (1.0f - v1c.x * invA);
    v1c.y = fminf(v1.y * 0.95f, 0.8f); den.y = 1.0f / (1.0f - v1c.y * invA);
    v1c.z = fminf(v1.z * 0.95f, 0.8f); den.z = 1.0f / (1.0f - v1c.z * invA);
    v1c.w = fminf(v1.w * 0.95f, 0.8f); den.w = 1.0f / (1.0f - v1c.w * invA);
    size_t o = (size_t)b * 3 * HW + pix;
#pragma unroll
    for (int c = 0; c < 3; c++) {
        float4 m = *(const float4*)(x + o);
        float4 y;
        y.x = fminf(fmaxf((m.x * 255.0f - v1c.x) * den.x, 0.0f), 1.0f);
        y.y = fminf(fmaxf((m.y * 255.0f - v1c.y) * den.y, 0.0f), 1.0f);
        y.z = fminf(fmaxf((m.z * 255.0f - v1c.z) * den.z, 0.0f), 1.0f);
        y.w = fminf(fmaxf((m.w * 255.0f - v1c.w) * den.w, 0.0f), 1.0f);
        *(float4*)(out + o) = y;
        o += HW;
    }
}

/* ---------------- launch ---------------- */

extern "C" void kernel_launch(void* const* d_in, const int* in_sizes, int n_in,
                              void* d_out, int out_size, void* d_ws, size_t ws_size,
                              hipStream_t stream) {
    const float* x = (const float*)d_in[0];
    float* out = (float*)d_out;

    unsigned* scal = (unsigned*)d_ws;                     /* [0]=minKey [1]=maxKey [2]=acandKey [3]=any */
    float* fscal = (float*)d_ws;                          /* [5]=A */
    unsigned* hist = (unsigned*)((char*)d_ws + 96);       /* [2000] */
    float* pbsum = (float*)((char*)d_ws + 8192);          /* [6144] block partials */
    float* planes = (float*)((char*)d_ws + 131072);
    float* P0 = planes + (size_t)0 * NPIX;  /* V1raw (I) */
    float* P1 = planes + (size_t)1 * NPIX;  /* mmean */
    float* P2 = planes + (size_t)2 * NPIX;  /* hmin; later HAB (with P3) */
    float* P3 = planes + (size_t)3 * NPIX;  /* p */
    float* P6 = planes + (size_t)6 * NPIX;  /* V1 */
    float4* F4 = (float4*)(planes + (size_t)4 * NPIX);    /* vertical field sums, P4..P7 */
    float2* HAB = (float2*)P2;                            /* ha,hb interleaved, P2..P3 */

    k_prep<<<NROWS, 256, 0, stream>>>(x, P0, P1, P2, pbsum, scal, hist);
    k_minv<<<BATCH * NCHM * WW / 256, 256, 0, stream>>>(P2, P3);
    k_kv1<<<NVB, 256, 0, stream>>>(P0, P3, F4);
    k_kh1<<<NROWS, 256, 0, stream>>>(F4, HAB);
    k_kv2<<<NVB, 256, 0, stream>>>(HAB, P0, P6, scal);
    k_hist<<<1024, 256, 0, stream>>>(P6, scal, hist);
    k_amax<<<1024, 256, 0, stream>>>(P6, P1, hist, scal);
    k_selA<<<1, 256, 0, stream>>>(scal, pbsum, fscal);
    k_final<<<NPIX / 1024, 256, 0, stream>>>(x, P6, fscal, out);
}